// Round 20
// baseline (1764.222 us; speedup 1.0000x reference)
//
#include <hip/hip_runtime.h>
#include <hip/hip_bf16.h>

using u16 = unsigned short;
using u32 = unsigned int;
using u8  = unsigned char;
using u64 = unsigned long long;
using bf16x8 = __attribute__((ext_vector_type(8))) short;
using f32x4  = __attribute__((ext_vector_type(4))) float;
using l2v    = __attribute__((ext_vector_type(2))) long;

namespace {
constexpr int BB   = 4;
constexpr int SEQ  = 2048;
constexpr int DIM  = 768;
constexpr int NH   = 4;
constexpr int DHD  = 192;   // DIM / NH
constexpr int VOC  = 32000;
constexpr int NLAY = 3;
constexpr int FFD  = 1024;
constexpr int ROWS = BB * SEQ;      // 8192
constexpr int NT2  = VOC / 256;     // 125 classifier n-tiles
constexpr int QKV = 3 * DIM;        // 2304
constexpr int BH  = BB * NH;        // 16
}

__device__ __forceinline__ float b2f(u16 u) { return __uint_as_float(((u32)u) << 16); }
__device__ __forceinline__ u16 f2b(float f) {
    u32 x = __float_as_uint(f);
    return (u16)((x + 0x7fffu + ((x >> 16) & 1u)) >> 16);
}

// f32 -> OCP e4m3fn, RNE, saturating.
__device__ __forceinline__ u32 f2e4m3(float f) {
    float af = fabsf(f);
    u32 sgn = (__float_as_uint(f) >> 24) & 0x80u;
    if (!(af < 448.f)) return sgn | 0x7Eu;
    int e = (int)((__float_as_uint(af) >> 23) & 0xff) - 127;
    if (e < -6) e = -6;
    float sc = __uint_as_float((u32)(130 - e) << 23);   // 2^(3-e)
    int code = __float2int_rn(af * sc) + ((e + 6) << 3);
    return sgn | (u32)code;
}
// e4m3fn -> f32
__device__ __forceinline__ float e4m3f(u8 v) {
    int e = (v >> 3) & 15, m = v & 7;
    float f = (e == 0) ? (float)m * 0.001953125f              // 2^-9
                       : __uint_as_float((u32)((e + 120) << 23) | ((u32)m << 20));
    return (v & 0x80u) ? -f : f;
}

__device__ __forceinline__ void gload16b(const u8* g, u8* l) {
    __builtin_amdgcn_global_load_lds(
        (const __attribute__((address_space(1))) u32*)g,
        (__attribute__((address_space(3))) u32*)l, 16, 0, 0);
}

// phase boundary: counted vmcnt (never 0 in steady state) + raw barrier.
#define PHASE_END(N) do {                                        \
    __builtin_amdgcn_sched_barrier(0);                           \
    asm volatile("s_waitcnt vmcnt(" #N ")" ::: "memory");        \
    __builtin_amdgcn_s_barrier();                                \
    asm volatile("" ::: "memory");                               \
    __builtin_amdgcn_sched_barrier(0);                           \
} while (0)

__device__ __forceinline__ float block_sum256(float v, float* sb) {
    #pragma unroll
    for (int off = 32; off > 0; off >>= 1) v += __shfl_down(v, off, 64);
    int lane = threadIdx.x & 63, w = threadIdx.x >> 6;
    if (lane == 0) sb[w] = v;
    __syncthreads();
    float r = sb[0] + sb[1] + sb[2] + sb[3];
    __syncthreads();
    return r;
}

// ---------------------------------------------------------------------------
// Scores GEMM fp8: 256x256 tile, K=192, BK=64, TRIANGULAR grid (36, 1, 16).
// A=Q (x4 fp8), B=K (x4 fp8), both row-stride QKV. b128 k-permutation:
// lane chunk lg holds 8B-units {2lg, 2lg+1} (bijection (e,lg)->2lg+e); read
// phys chunk = lg ^ (row&3), source pre-swizzled chunk ^= row&3 (bank-uniform:
// 8 events/bank = b128 minimum, enumerated). Single phase per K-step (3 steps;
// epilogue dominates). Epilogue: v = acc/16*0.05; mask -> -30; e=exp(v);
// P = fp8(e*16); per-64-row colsum partials in exact f32.
// ---------------------------------------------------------------------------
__global__ __launch_bounds__(512, 2)
void gemm256s_f8(const u8* __restrict__ qkvq, const int* __restrict__ xtok,
                 u8* __restrict__ Pq, float* __restrict__ cpart)
{
    __shared__ __align__(16) u8 sA8[2][256 * 64];
    __shared__ __align__(16) u8 sB8[2][256 * 64];

    int t = threadIdx.x, w = t >> 6, lane = t & 63;
    int wr = w >> 2, wcn = w & 3;
    int lr = lane & 15, lg = lane >> 4;

    int z = blockIdx.z, bz = z >> 2, hz = z & 3;
    const u8* Qb = qkvq + (size_t)bz * SEQ * QKV + hz * DHD;
    const u8* Kb = Qb + DIM;
    size_t Coff = (size_t)z * SEQ * SEQ;

    int by = 7;
    {
        int tix = blockIdx.x;
        while (by * (by + 1) / 2 > tix) by--;
    }
    int bx = blockIdx.x - by * (by + 1) / 2;
    int m0 = by * 256, n0 = bx * 256;

    int sr4 = lane >> 2;                       // row within 16-row instr group
    int sc4 = ((lane & 3) ^ (sr4 & 3)) * 16;   // pre-swizzled source chunk

    f32x4 acc[8][4];
    #pragma unroll
    for (int i = 0; i < 8; i++)
        #pragma unroll
        for (int j = 0; j < 4; j++) acc[i][j] = (f32x4){0.f, 0.f, 0.f, 0.f};

    auto stA = [&](int buf, int k0) {
        #pragma unroll
        for (int i = 0; i < 2; i++) {
            int rb = i * 128 + w * 16;
            gload16b(Qb + (size_t)(m0 + rb + sr4) * QKV + k0 + sc4,
                     &sA8[buf][rb * 64]);
        }
    };
    auto stB = [&](int buf, int k0) {
        #pragma unroll
        for (int i = 0; i < 2; i++) {
            int rb = i * 128 + w * 16;
            gload16b(Kb + (size_t)(n0 + rb + sr4) * QKV + k0 + sc4,
                     &sB8[buf][rb * 64]);
        }
    };

    stA(0, 0); stB(0, 0);
    PHASE_END(0);

    #pragma unroll
    for (int kt = 0; kt < 3; ++kt) {           // K = 192, BK = 64
        int cur = kt & 1;
        int off = (lg ^ (lr & 3)) * 16;
        l2v a[8], b[4];
        #pragma unroll
        for (int mi = 0; mi < 8; mi++)
            a[mi] = *(const l2v*)&sA8[cur][(wr * 128 + mi * 16 + lr) * 64 + off];
        #pragma unroll
        for (int ni = 0; ni < 4; ni++)
            b[ni] = *(const l2v*)&sB8[cur][(wcn * 64 + ni * 16 + lr) * 64 + off];
        if (kt < 2) { stA(cur ^ 1, (kt + 1) * 64); stB(cur ^ 1, (kt + 1) * 64); }
        __builtin_amdgcn_s_setprio(1);
        #pragma unroll
        for (int e = 0; e < 2; e++)
            #pragma unroll
            for (int mi = 0; mi < 8; mi++)
                #pragma unroll
                for (int ni = 0; ni < 4; ni++)
                    acc[mi][ni] = __builtin_amdgcn_mfma_f32_16x16x32_fp8_fp8(
                        a[mi][e], b[ni][e], acc[mi][ni], 0, 0, 0);
        __builtin_amdgcn_s_setprio(0);
        PHASE_END(0);
    }

    // epilogue
    const int* xb = xtok + (size_t)bz * SEQ;
    float cs[2][4] = {{0.f,0.f,0.f,0.f},{0.f,0.f,0.f,0.f}};
    #pragma unroll
    for (int mi = 0; mi < 8; mi++)
        #pragma unroll
        for (int j = 0; j < 4; j++) {
            int grow = m0 + wr * 128 + mi * 16 + lg * 4 + j;
            int xz = xb[grow];
            #pragma unroll
            for (int ni = 0; ni < 4; ni++) {
                int gcol = n0 + wcn * 64 + ni * 16 + lr;
                float v = acc[mi][ni][j] * 0.003125f;   // /16 dequant, /20 scale
                if (gcol > grow || xz == 0) v = -30.f;
                float e = __expf(v);
                Pq[Coff + (size_t)grow * SEQ + gcol] = (u8)f2e4m3(e * 16.f);
                cs[mi >> 2][ni] += e;
            }
        }
    #pragma unroll
    for (int h = 0; h < 2; h++)
        #pragma unroll
        for (int ni = 0; ni < 4; ni++) {
            float c = cs[h][ni];
            c += __shfl_xor(c, 16, 64);
            c += __shfl_xor(c, 32, 64);
            if (lg == 0) {
                int p = (m0 >> 6) + wr * 2 + h;
                cpart[((size_t)p * BH + z) * SEQ + n0 + wcn * 64 + ni * 16 + lr] = c;
            }
        }
}

// ---------------------------------------------------------------------------
// Classifier GEMM in fp8-e4m3 (round-16 verified): 256x256, BK=128,
// counted-vmcnt 2-phase, b128 k-permutation reads (conflict-free).
// A is h*4 in fp8, B is W*16 in fp8 -> acc/64 in epilogue.
// ---------------------------------------------------------------------------
__global__ __launch_bounds__(512, 2)
void gemm256_f8(const u8* __restrict__ Aq, const u8* __restrict__ Bq, int K,
                const float* __restrict__ bias,
                const int* __restrict__ label,
                float* __restrict__ partials, float* __restrict__ picked)
{
    __shared__ __align__(16) u8 sA8[2][256 * 128];
    __shared__ __align__(16) u8 sB8[2][2][128 * 128];

    int t = threadIdx.x, w = t >> 6, lane = t & 63;
    int wr = w >> 2, wcn = w & 3;
    int lr = lane & 15, lg = lane >> 4;
    int rx = lr & 7;

    int bx = blockIdx.x, by = blockIdx.y;
    {
        int pid = by * gridDim.x + bx;
        int xcd = pid & 7, s = pid >> 3;
        bx = s >> 2;
        by = xcd * 4 + (s & 3);
    }
    int m0 = by * 256, n0 = bx * 256;

    int srow8 = lane >> 3;
    int scol8 = ((lane & 7) ^ srow8) * 16;   // pre-swizzled source (chunk^row&7)

    f32x4 acc[8][4];
    #pragma unroll
    for (int i = 0; i < 8; i++)
        #pragma unroll
        for (int j = 0; j < 4; j++) acc[i][j] = (f32x4){0.f, 0.f, 0.f, 0.f};

    auto stageA = [&](int buf, int k0) {
        #pragma unroll
        for (int i = 0; i < 4; i++) {
            int rb = i * 64 + w * 8;
            gload16b(Aq + (size_t)(m0 + rb + srow8) * DIM + k0 + scol8,
                     &sA8[buf][rb * 128]);
        }
    };
    auto stageB = [&](int buf, int k0, int h) {
        #pragma unroll
        for (int j = 0; j < 2; j++) {
            int rh = j * 64 + w * 8;
            int rbase = (rh >> 5) * 64 + h * 32 + (rh & 31);
            gload16b(Bq + (size_t)(n0 + rbase + srow8) * DIM + k0 + scol8,
                     &sB8[buf][h][rh * 128]);
        }
    };

    int nt = K >> 7;   // BK = 128
    stageA(0, 0); stageB(0, 0, 0); stageB(0, 0, 1);
    PHASE_END(0);

    for (int kt = 0; kt < nt; ++kt) {
        int cur = kt & 1;
        int kn = (kt + 1) << 7;
        bool st = (kt + 1 < nt);
        // ---------- phase 0: ni{0,1} ----------
        l2v aa[2][8], bb[2][2];
        #pragma unroll
        for (int h = 0; h < 2; h++) {
            int off = ((2 * lg + h) ^ rx) * 16;
            #pragma unroll
            for (int mi = 0; mi < 8; mi++)
                aa[h][mi] = *(const l2v*)&sA8[cur][(wr * 128 + mi * 16 + lr) * 128 + off];
            #pragma unroll
            for (int ni = 0; ni < 2; ni++)
                bb[h][ni] = *(const l2v*)&sB8[cur][0][(wcn * 32 + ni * 16 + lr) * 128 + off];
        }
        if (st) { stageA(cur ^ 1, kn); stageB(cur ^ 1, kn, 0); }
        __builtin_amdgcn_s_setprio(1);
        #pragma unroll
        for (int h = 0; h < 2; h++)
            #pragma unroll
            for (int e = 0; e < 2; e++)
                #pragma unroll
                for (int mi = 0; mi < 8; mi++)
                    #pragma unroll
                    for (int ni = 0; ni < 2; ni++)
                        acc[mi][ni] = __builtin_amdgcn_mfma_f32_16x16x32_fp8_fp8(
                            aa[h][mi][e], bb[h][ni][e], acc[mi][ni], 0, 0, 0);
        __builtin_amdgcn_s_setprio(0);
        if (st) PHASE_END(6); else PHASE_END(0);
        // ---------- phase 1: ni{2,3} ----------
        l2v bc[2][2];
        #pragma unroll
        for (int h = 0; h < 2; h++) {
            int off = ((2 * lg + h) ^ rx) * 16;
            #pragma unroll
            for (int ni = 0; ni < 2; ni++)
                bc[h][ni] = *(const l2v*)&sB8[cur][1][(wcn * 32 + ni * 16 + lr) * 128 + off];
        }
        if (st) stageB(cur ^ 1, kn, 1);
        __builtin_amdgcn_s_setprio(1);
        #pragma unroll
        for (int h = 0; h < 2; h++)
            #pragma unroll
            for (int e = 0; e < 2; e++)
                #pragma unroll
                for (int mi = 0; mi < 8; mi++)
                    #pragma unroll
                    for (int ni = 0; ni < 2; ni++)
                        acc[mi][ni + 2] = __builtin_amdgcn_mfma_f32_16x16x32_fp8_fp8(
                            aa[h][mi][e], bc[h][ni][e], acc[mi][ni + 2], 0, 0, 0);
        __builtin_amdgcn_s_setprio(0);
        if (st) PHASE_END(2); else PHASE_END(0);
    }

    // epilogue: unscale + bias, label pick, per-row (max,sumexp) partials
    #pragma unroll
    for (int mi = 0; mi < 8; mi++)
        #pragma unroll
        for (int ni = 0; ni < 4; ni++) {
            int gcol = n0 + wcn * 64 + ni * 16 + lr;
            float bcol = bias[gcol];
            #pragma unroll
            for (int j = 0; j < 4; j++)
                acc[mi][ni][j] = acc[mi][ni][j] * (1.f / 64.f) + bcol;
        }
    #pragma unroll
    for (int mi = 0; mi < 8; mi++)
        #pragma unroll
        for (int j = 0; j < 4; j++) {
            int grow = m0 + wr * 128 + mi * 16 + lg * 4 + j;
            int lab = label[grow];
            #pragma unroll
            for (int ni = 0; ni < 4; ni++) {
                int gcol = n0 + wcn * 64 + ni * 16 + lr;
                if (lab == gcol) picked[grow] = acc[mi][ni][j];
            }
        }
    float* red = (float*)sA8;  // [256 rows][4 wcn][2]
    #pragma unroll
    for (int mi = 0; mi < 8; mi++)
        #pragma unroll
        for (int j = 0; j < 4; j++) {
            float mx = -1e30f;
            #pragma unroll
            for (int ni = 0; ni < 4; ni++) mx = fmaxf(mx, acc[mi][ni][j]);
            #pragma unroll
            for (int off = 1; off < 16; off <<= 1)
                mx = fmaxf(mx, __shfl_xor(mx, off, 64));
            float ss = 0.f;
            #pragma unroll
            for (int ni = 0; ni < 4; ni++) ss += __expf(acc[mi][ni][j] - mx);
            #pragma unroll
            for (int off = 1; off < 16; off <<= 1) ss += __shfl_xor(ss, off, 64);
            if (lr == 0) {
                int rloc = wr * 128 + mi * 16 + lg * 4 + j;
                red[rloc * 8 + wcn * 2 + 0] = mx;
                red[rloc * 8 + wcn * 2 + 1] = ss;
            }
        }
    __syncthreads();
    if (t < 256) {
        float Mv = -1e30f;
        #pragma unroll
        for (int q = 0; q < 4; q++) Mv = fmaxf(Mv, red[t * 8 + q * 2]);
        float Sv = 0.f;
        #pragma unroll
        for (int q = 0; q < 4; q++)
            Sv += red[t * 8 + q * 2 + 1] * __expf(red[t * 8 + q * 2] - Mv);
        size_t row = (size_t)(m0 + t);
        partials[(row * NT2 + bx) * 2 + 0] = Mv;
        partials[(row * NT2 + bx) * 2 + 1] = Sv;
    }
}

// ---------------------------------------------------------------------------
// 128x128 NT GEMM fp8 (QKV / FF1 / FF2): BK=128, counted-vmcnt 2-phase,
// b128 k-perm reads. A = act*4 fp8 (row stride K), B = W*16 fp8 [N][K]
// -> acc/64. Epilogue: +bias, optional relu; bf16 (Cb) and/or fp8*4 (Cq).
// XCD-banded remap (gridDim.y == 64).
// ---------------------------------------------------------------------------
__global__ __launch_bounds__(256)
void gemm128_f8(const u8* __restrict__ Aq, const u8* __restrict__ Bq,
                int K,
                const float* __restrict__ bias,
                u16* __restrict__ Cb, u8* __restrict__ Cq, long ldc, int relu)
{
    __shared__ __align__(16) u8 sA8[2][128 * 128];
    __shared__ __align__(16) u8 sB8[2][2][64 * 128];

    int t = threadIdx.x, w = t >> 6, lane = t & 63;
    int wr = w >> 1, wc = w & 1;
    int lr = lane & 15, lg = lane >> 4;
    int rx = lr & 7;

    int bx = blockIdx.x, by = blockIdx.y;
    {
        int pid = by * gridDim.x + bx;
        int xcd = pid & 7, s = pid >> 3;
        bx = s >> 3;
        by = xcd * 8 + (s & 7);
    }
    int m0 = by * 128, n0 = bx * 128;

    int srow8 = lane >> 3;
    int scol8 = ((lane & 7) ^ srow8) * 16;

    f32x4 acc[4][4];
    #pragma unroll
    for (int i = 0; i < 4; i++)
        #pragma unroll
        for (int j = 0; j < 4; j++) acc[i][j] = (f32x4){0.f, 0.f, 0.f, 0.f};

    auto stageA = [&](int buf, int k0) {
        #pragma unroll
        for (int i = 0; i < 4; i++) {
            int rb = i * 32 + w * 8;
            gload16b(Aq + (size_t)(m0 + rb + srow8) * K + k0 + scol8,
                     &sA8[buf][rb * 128]);
        }
    };
    auto stageB = [&](int buf, int k0, int h) {
        #pragma unroll
        for (int j = 0; j < 2; j++) {
            int rh = j * 32 + w * 8;               // storage row (uniform)
            int rbase = j * 64 + h * 32 + w * 8;   // tile row base
            gload16b(Bq + (size_t)(n0 + rbase + srow8) * K + k0 + scol8,
                     &sB8[buf][h][rh * 128]);
        }
    };

    int nt = K >> 7;   // BK = 128
    stageA(0, 0); stageB(0, 0, 0); stageB(0, 0, 1);
    PHASE_END(0);

    for (int kt = 0; kt < nt; ++kt) {
        int cur = kt & 1;
        int kn = (kt + 1) << 7;
        bool st = (kt + 1 < nt);
        l2v aa[2][4], bb[2][2];
        #pragma unroll
        for (int h = 0; h < 2; h++) {
            int off = ((2 * lg + h) ^ rx) * 16;
            #pragma unroll
            for (int mi = 0; mi < 4; mi++)
                aa[h][mi] = *(const l2v*)&sA8[cur][(wr * 64 + mi * 16 + lr) * 128 + off];
            #pragma unroll
            for (int ni = 0; ni < 2; ni++)
                bb[h][ni] = *(const l2v*)&sB8[cur][0][(wc * 32 + ni * 16 + lr) * 128 + off];
        }
        if (st) { stageA(cur ^ 1, kn); stageB(cur ^ 1, kn, 0); }
        __builtin_amdgcn_s_setprio(1);
        #pragma unroll
        for (int h = 0; h < 2; h++)
            #pragma unroll
            for (int e = 0; e < 2; e++)
                #pragma unroll
                for (int mi = 0; mi < 4; mi++)
                    #pragma unroll
                    for (int ni = 0; ni < 2; ni++)
                        acc[mi][ni] = __builtin_amdgcn_mfma_f32_16x16x32_fp8_fp8(
                            aa[h][mi][e], bb[h][ni][e], acc[mi][ni], 0, 0, 0);
        __builtin_amdgcn_s_setprio(0);
        if (st) PHASE_END(6); else PHASE_END(0);

        l2v bc[2][2];
        #pragma unroll
        for (int h = 0; h < 2; h++) {
            int off = ((2 * lg + h) ^ rx) * 16;
            #pragma unroll
            for (int ni = 0; ni < 2; ni++)
                bc[h][ni] = *(const l2v*)&sB8[cur][1][(wc * 32 + ni * 16 + lr) * 128 + off];
        }
        if (st) stageB(cur ^ 1, kn, 1);
        __builtin_amdgcn_s_setprio(1);
        #pragma unroll
        for (int h = 0; h < 2; h++)
            #pragma unroll
            for (int e = 0; e < 2; e++)
                #pragma unroll
                for (int mi = 0; mi < 4; mi++)
                    #pragma unroll
                    for (int ni = 0; ni < 2; ni++)
                        acc[mi][ni + 2] = __builtin_amdgcn_mfma_f32_16x16x32_fp8_fp8(
                            aa[h][mi][e], bc[h][ni][e], acc[mi][ni + 2], 0, 0, 0);
        __builtin_amdgcn_s_setprio(0);
        if (st) PHASE_END(2); else PHASE_END(0);
    }

    #pragma unroll
    for (int mi = 0; mi < 4; mi++)
        #pragma unroll
        for (int ni = 0; ni < 4; ni++)
            #pragma unroll
            for (int j = 0; j < 4; j++) {
                int grow = m0 + wr * 64 + mi * 16 + lg * 4 + j;
                int gcol = n0 + wc * 64 + ni * 16 + lr;
                float v = acc[mi][ni][j] * (1.f / 64.f) + bias[gcol];
                if (relu) v = fmaxf(v, 0.f);
                size_t ci = (size_t)grow * ldc + gcol;
                if (Cb) Cb[ci] = f2b(v);
                if (Cq) Cq[ci] = (u8)f2e4m3(v * 4.f);
            }
}

// ---------------------------------------------------------------------------
// PV GEMM fp8: 128x128 tile, z-batched (z = b*NH+h), A = P (x16 fp8, stride
// SEQ), B = vT (x16 fp8, stride SEQ, d-rows clamped to DHD-1), causal
// K-truncation (nt = by+1 at BK=128), balanced by-pairing. acc/256 -> bf16.
// Same counted-vmcnt ledger as gemm128_f8.
// ---------------------------------------------------------------------------
__global__ __launch_bounds__(256)
void gemm128pv_f8(const u8* __restrict__ Pq, const u8* __restrict__ vTq,
                  u16* __restrict__ Cb)
{
    __shared__ __align__(16) u8 sA8[2][128 * 128];
    __shared__ __align__(16) u8 sB8[2][2][64 * 128];

    int t = threadIdx.x, w = t >> 6, lane = t & 63;
    int wr = w >> 1, wc = w & 1;
    int lr = lane & 15, lg = lane >> 4;
    int rx = lr & 7;

    int z = blockIdx.z, bz = z >> 2, hz = z & 3;
    const u8* Ab = Pq + (size_t)z * SEQ * SEQ;
    const u8* Bb = vTq + (size_t)z * DHD * SEQ;
    size_t Coff = (size_t)bz * SEQ * DIM + (size_t)hz * DHD;

    int bx = blockIdx.x, by = blockIdx.y;
    by = (by & 1) ? (15 - (by >> 1)) : (by >> 1);   // heavy/light pairing
    int m0 = by * 128, n0 = bx * 128;

    int srow8 = lane >> 3;
    int scol8 = ((lane & 7) ^ srow8) * 16;

    f32x4 acc[4][4];
    #pragma unroll
    for (int i = 0; i < 4; i++)
        #pragma unroll
        for (int j = 0; j < 4; j++) acc[i][j] = (f32x4){0.f, 0.f, 0.f, 0.f};

    auto stageA = [&](int buf, int k0) {
        #pragma unroll
        for (int i = 0; i < 4; i++) {
            int rb = i * 32 + w * 8;
            gload16b(Ab + (size_t)(m0 + rb + srow8) * SEQ + k0 + scol8,
                     &sA8[buf][rb * 128]);
        }
    };
    auto stageB = [&](int buf, int k0, int h) {
        #pragma unroll
        for (int j = 0; j < 2; j++) {
            int rh = j * 32 + w * 8;
            int rbase = j * 64 + h * 32 + w * 8;
            int row = n0 + rbase + srow8;
            if (row > DHD - 1) row = DHD - 1;
            gload16b(Bb + (size_t)row * SEQ + k0 + scol8,
                     &sB8[buf][h][rh * 128]);
        }
    };

    int nt = by + 1;   // K_eff = (by+1)*128 (causal), BK = 128
    stageA(0, 0); stageB(0, 0, 0); stageB(0, 0, 1);
    PHASE_END(0);

    for (int kt = 0; kt < nt; ++kt) {
        int cur = kt & 1;
        int kn = (kt + 1) << 7;
        bool st = (kt + 1 < nt);
        l2v aa[2][4], bb[2][2];
        #pragma unroll
        for (int h = 0; h < 2; h++) {
            int off = ((2 * lg + h) ^ rx) * 16;
            #pragma unroll
            for (int mi = 0; mi < 4; mi++)
                aa[h][mi] = *(const l2v*)&sA8[cur][(wr * 64 + mi * 16 + lr) * 128 + off];
            #pragma unroll
            for (int ni = 0; ni < 2; ni++)
                bb[h][ni] = *(const l2v*)&sB8[cur][0][(wc * 32 + ni * 16 + lr) * 128 + off];
        }
        if (st) { stageA(cur ^ 1, kn); stageB(cur ^ 1, kn, 0); }
        __builtin_amdgcn_s_setprio(1);
        #pragma unroll
        for (int h = 0; h < 2; h++)
            #pragma unroll
            for (int e = 0; e < 2; e++)
                #pragma unroll
                for (int mi = 0; mi < 4; mi++)
                    #pragma unroll
                    for (int ni = 0; ni < 2; ni++)
                        acc[mi][ni] = __builtin_amdgcn_mfma_f32_16x16x32_fp8_fp8(
                            aa[h][mi][e], bb[h][ni][e], acc[mi][ni], 0, 0, 0);
        __builtin_amdgcn_s_setprio(0);
        if (st) PHASE_END(6); else PHASE_END(0);

        l2v bc[2][2];
        #pragma unroll
        for (int h = 0; h < 2; h++) {
            int off = ((2 * lg + h) ^ rx) * 16;
            #pragma unroll
            for (int ni = 0; ni < 2; ni++)
                bc[h][ni] = *(const l2v*)&sB8[cur][1][(wc * 32 + ni * 16 + lr) * 128 + off];
        }
        if (st) stageB(cur ^ 1, kn, 1);
        __builtin_amdgcn_s_setprio(1);
        #pragma unroll
        for (int h = 0; h < 2; h++)
            #pragma unroll
            for (int e = 0; e < 2; e++)
                #pragma unroll
                for (int mi = 0; mi < 4; mi++)
                    #pragma unroll
                    for (int ni = 0; ni < 2; ni++)
                        acc[mi][ni + 2] = __builtin_amdgcn_mfma_f32_16x16x32_fp8_fp8(
                            aa[h][mi][e], bc[h][ni][e], acc[mi][ni + 2], 0, 0, 0);
        __builtin_amdgcn_s_setprio(0);
        if (st) PHASE_END(2); else PHASE_END(0);
    }

    #pragma unroll
    for (int mi = 0; mi < 4; mi++)
        #pragma unroll
        for (int ni = 0; ni < 4; ni++)
            #pragma unroll
            for (int j = 0; j < 4; j++) {
                int grow = m0 + wr * 64 + mi * 16 + lg * 4 + j;
                int gcol = n0 + wc * 64 + ni * 16 + lr;
                if (gcol < DHD)
                    Cb[Coff + (size_t)grow * DIM + gcol] =
                        f2b(acc[mi][ni][j] * (1.f / 256.f));
            }
}

// ---------------------------------------------------------------------------
__global__ __launch_bounds__(256)
void embed_k(const int* __restrict__ x, const float* __restrict__ tok,
             const float* __restrict__ pos, u16* __restrict__ hb, u8* __restrict__ hq)
{
    int row = blockIdx.x, t = threadIdx.x;
    int token = x[row];
    int s = row & (SEQ - 1);
    size_t base = (size_t)row * DIM;
    #pragma unroll
    for (int e = 0; e < 3; e++) {
        int d = t + e * 256;
        float v = tok[(size_t)token * DIM + d] + pos[(size_t)s * DIM + d];
        hb[base + d] = f2b(v);
        hq[base + d] = (u8)f2e4m3(v * 4.f);
    }
}

// h' = LN(res + add), bf16 in, bf16 + fp8(x4) out, f32 stats. In-place safe.
__global__ __launch_bounds__(256)
void resid_ln(const u16* __restrict__ res, const u16* __restrict__ add,
              const float* __restrict__ g, const float* __restrict__ b,
              u16* __restrict__ out, u8* __restrict__ outq)
{
    __shared__ float sb[4];
    int row = blockIdx.x, t = threadIdx.x;
    size_t base = (size_t)row * DIM;
    float x0 = 0.f, x1 = 0.f, x2 = 0.f, x3 = 0.f;
    if (t < 192) {
        ushort4 r4 = *(const ushort4*)&res[base + t * 4];
        ushort4 a4 = *(const ushort4*)&add[base + t * 4];
        x0 = b2f(r4.x) + b2f(a4.x);
        x1 = b2f(r4.y) + b2f(a4.y);
        x2 = b2f(r4.z) + b2f(a4.z);
        x3 = b2f(r4.w) + b2f(a4.w);
    }
    float mean = block_sum256(x0 + x1 + x2 + x3, sb) * (1.f / DIM);
    float d0 = x0 - mean, d1 = x1 - mean, d2 = x2 - mean, d3 = x3 - mean;
    float var = block_sum256(t < 192 ? d0*d0 + d1*d1 + d2*d2 + d3*d3 : 0.f, sb) * (1.f / DIM);
    float rs = rsqrtf(var + 1e-5f);
    if (t < 192) {
        float4 gv = *(const float4*)&g[t * 4];
        float4 bv = *(const float4*)&b[t * 4];
        float y0 = d0 * rs * gv.x + bv.x, y1 = d1 * rs * gv.y + bv.y;
        float y2 = d2 * rs * gv.z + bv.z, y3 = d3 * rs * gv.w + bv.w;
        ushort4 ob = {f2b(y0), f2b(y1), f2b(y2), f2b(y3)};
        *(ushort4*)&out[base + t * 4] = ob;
        uchar4 oq = {(u8)f2e4m3(y0 * 4.f), (u8)f2e4m3(y1 * 4.f),
                     (u8)f2e4m3(y2 * 4.f), (u8)f2e4m3(y3 * 4.f)};
        *(uchar4*)&outq[base + t * 4] = oq;
    }
}

// V (fp8 x4, stride ldv) -> vT (fp8 x16) [B*H][DH][S], scaled by 1/colsum.
__global__ void v_transpose(const u8* __restrict__ v, long ldv,
                            const float* __restrict__ cpart, u8* __restrict__ vT)
{
    __shared__ u8 tile[32][33];
    int z = blockIdx.z;
    int b = z >> 2, h = z & 3;
    int s0 = blockIdx.x * 32, d0 = blockIdx.y * 32;
    int tx = threadIdx.x, ty = threadIdx.y;
    #pragma unroll
    for (int i = 0; i < 4; i++)
        tile[ty + i * 8][tx] = v[((size_t)b * SEQ + s0 + ty + i * 8) * ldv + h * DHD + d0 + tx];
    int scol = s0 + tx;
    int pmin = (scol >> 8) * 4;
    float sv = 0.f;
    for (int p = pmin; p < 32; p++) sv += cpart[((size_t)p * BH + z) * SEQ + scol];
    float sc = 4.f / sv;   // dequant x0.25 * requant x16 = x4 / colsum
    __syncthreads();
    #pragma unroll
    for (int i = 0; i < 4; i++)
        vT[((size_t)z * DHD + d0 + ty + i * 8) * SEQ + scol] =
            (u8)f2e4m3(e4m3f(tile[tx][ty + i * 8]) * sc);
}

// W [K][N] f32 -> Wt [N][K] fp8 (x16), z-batched
__global__ void wt_cvt8_z(const float* __restrict__ src0, long sSrc,
                          u8* __restrict__ dst0, long sDst, int K, int N)
{
    __shared__ float tile[32][33];
    const float* src = src0 + (size_t)blockIdx.z * sSrc;
    u8* dst = dst0 + (size_t)blockIdx.z * sDst;
    int n0 = blockIdx.x * 32, k0 = blockIdx.y * 32;
    int tx = threadIdx.x, ty = threadIdx.y;
    #pragma unroll
    for (int i = 0; i < 4; i++)
        tile[ty + i * 8][tx] = src[(size_t)(k0 + ty + i * 8) * N + n0 + tx];
    __syncthreads();
    #pragma unroll
    for (int i = 0; i < 4; i++)
        dst[(size_t)(n0 + ty + i * 8) * K + k0 + tx] =
            (u8)f2e4m3(tile[tx][ty + i * 8] * 16.f);
}

__global__ __launch_bounds__(256)
void bias_cat(const float* __restrict__ bq, const float* __restrict__ bk,
              const float* __restrict__ bv, float* __restrict__ dst)
{
    int ij = blockIdx.x, t = threadIdx.x;
    #pragma unroll
    for (int e = 0; e < 3; e++) {
        int d = t + e * 256;
        dst[(size_t)ij * QKV + d]            = bq[(size_t)ij * DIM + d];
        dst[(size_t)ij * QKV + DIM + d]      = bk[(size_t)ij * DIM + d];
        dst[(size_t)ij * QKV + 2 * DIM + d]  = bv[(size_t)ij * DIM + d];
    }
}

__global__ __launch_bounds__(256)
void lse_merge(const float* __restrict__ partials, float* __restrict__ lse)
{
    __shared__ float sm[4], ssum[4];
    int row = blockIdx.x, t = threadIdx.x;
    float m = -1e30f, s = 0.f;
    if (t < NT2) {
        const float* p = partials + ((size_t)row * NT2 + t) * 2;
        m = p[0]; s = p[1];
    }
    #pragma unroll
    for (int off = 1; off < 64; off <<= 1) {
        float om = __shfl_xor(m, off, 64), os = __shfl_xor(s, off, 64);
        float M = fmaxf(m, om);
        s = s * __expf(m - M) + os * __expf(om - M);
        m = M;
    }
    int lane = t & 63, w = t >> 6;
    if (lane == 0) { sm[w] = m; ssum[w] = s; }
    __syncthreads();
    if (t == 0) {
        float M = fmaxf(fmaxf(sm[0], sm[1]), fmaxf(sm[2], sm[3]));
        float S = ssum[0] * __expf(sm[0] - M) + ssum[1] * __expf(sm[1] - M) +
                  ssum[2] * __expf(sm[2] - M) + ssum[3] * __expf(sm[3] - M);
        lse[row] = M + __logf(S);
    }
}

__global__ __launch_bounds__(256)
void loss_k(const float* __restrict__ lse, const float* __restrict__ picked,
            float* __restrict__ out)
{
    __shared__ float sb[4];
    int t = threadIdx.x;
    float a = 0.f;
    for (int r = t; r < ROWS; r += 256) a += lse[r] - picked[r];
    float tot = block_sum256(a, sb);
    if (t == 0) out[0] = tot / (float)ROWS;
}

// ---------------------------------------------------------------------------
extern "C" void kernel_launch(void* const* d_in, const int* in_sizes, int n_in,
                              void* d_out, int out_size, void* d_ws, size_t ws_size,
                              hipStream_t stream)
{
    (void)in_sizes; (void)n_in; (void)out_size; (void)ws_size;
    const int*   x     = (const int*)d_in[0];
    const int*   label = (const int*)d_in[1];
    const float* tok   = (const float*)d_in[2];
    const float* pos   = (const float*)d_in[3];
    const float* Wq    = (const float*)d_in[4];
    const float* bq    = (const float*)d_in[5];
    const float* Wk    = (const float*)d_in[6];
    const float* bk    = (const float*)d_in[7];
    const float* Wv    = (const float*)d_in[8];
    const float* bv    = (const float*)d_in[9];
    const float* ln_g  = (const float*)d_in[10];
    const float* ln_b  = (const float*)d_in[11];
    const float* W1    = (const float*)d_in[12];
    const float* b1    = (const float*)d_in[13];
    const float* W2    = (const float*)d_in[14];
    const float* b2    = (const float*)d_in[15];
    const float* f_g   = (const float*)d_in[16];
    const float* f_b   = (const float*)d_in[17];
    const float* Wcls  = (const float*)d_in[18];
    const float* bcls  = (const float*)d_in[19];

    char* p = (char*)d_ws;
    auto alloc = [&](size_t bytes) -> char* {
        char* r = p;
        p += (bytes + 255) & ~(size_t)255;
        return r;
    };
    u16* hb     = (u16*)alloc((size_t)ROWS * DIM * 2);   // h stream (bf16)
    u8*  hq     = (u8*)alloc((size_t)ROWS * DIM);        // h stream (fp8 x4)
    u16* ob     = (u16*)alloc((size_t)ROWS * DIM * 2);   // block output (bf16)
    u8*  qkvq   = (u8*)alloc((size_t)ROWS * QKV);        // QKV out (fp8 x4)
    u8*  vTq    = (u8*)alloc((size_t)BH * DHD * SEQ);    // vT (fp8 x16)
    u8*  ff1q   = (u8*)alloc((size_t)ROWS * FFD);        // FF1 out (fp8 x4)
    u8*  wbufq  = (u8*)alloc((size_t)BH * SEQ * SEQ);    // P (fp8 x16)
    u8*  WqkvT8 = (u8*)alloc((size_t)6 * QKV * DIM);
    u8*  W1T8   = (u8*)alloc((size_t)NLAY * DIM * FFD);
    u8*  W2T8   = (u8*)alloc((size_t)NLAY * FFD * DIM);
    u8*  WcT8   = (u8*)alloc((size_t)DIM * VOC);
    float* bqkv = (float*)alloc((size_t)6 * QKV * 4);
    float* cpart= (float*)alloc((size_t)32 * BH * SEQ * 4);
    float* partials = (float*)alloc((size_t)ROWS * NT2 * 2 * 4);
    float* picked   = (float*)alloc((size_t)ROWS * 4);
    float* lsev     = (float*)alloc((size_t)ROWS * 4);

    dim3 t32(32, 8, 1);
    wt_cvt8_z<<<dim3(DIM / 32, DIM / 32, 6), t32, 0, stream>>>(
        Wq, (long)DIM * DIM, WqkvT8, (long)QKV * DIM, DIM, DIM);
    wt_cvt8_z<<<dim3(DIM / 32, DIM / 32, 6), t32, 0, stream>>>(
        Wk, (long)DIM * DIM, WqkvT8 + (size_t)DIM * DIM, (long)QKV * DIM, DIM, DIM);
    wt_cvt8_z<<<dim3(DIM / 32, DIM / 32, 6), t32, 0, stream>>>(
        Wv, (long)DIM * DIM, WqkvT8 + (size_t)2 * DIM * DIM, (long)QKV * DIM, DIM, DIM);
    wt_cvt8_z<<<dim3(FFD / 32, DIM / 32, NLAY), t32, 0, stream>>>(
        W1, (long)DIM * FFD, W1T8, (long)DIM * FFD, DIM, FFD);
    wt_cvt8_z<<<dim3(DIM / 32, FFD / 32, NLAY), t32, 0, stream>>>(
        W2, (long)FFD * DIM, W2T8, (long)FFD * DIM, FFD, DIM);
    wt_cvt8_z<<<dim3(VOC / 32, DIM / 32, 1), t32, 0, stream>>>(
        Wcls, 0L, WcT8, 0L, DIM, VOC);
    bias_cat<<<6, 256, 0, stream>>>(bq, bk, bv, bqkv);

    embed_k<<<ROWS, 256, 0, stream>>>(x, tok, pos, hb, hq);

    for (int i = 0; i < NLAY; i++) {
        for (int j = 0; j < 2; j++) {
            int ij = i * 2 + j;
            // fused QKV projection (fp8 in, fp8 x4 out [ROWS][2304])
            gemm128_f8<<<dim3(QKV / 128, ROWS / 128, 1), 256, 0, stream>>>(
                hq, WqkvT8 + (size_t)ij * QKV * DIM, DIM,
                bqkv + (size_t)ij * QKV, nullptr, qkvq, QKV, 0);
            // P = fp8(exp(masked(QK^T/20))*16) + colsum partials — triangular
            gemm256s_f8<<<dim3(36, 1, BH), 512, 0, stream>>>(
                qkvq, x, wbufq, cpart);
            // vT = transpose(V)/colsum (fp8 in/out)
            v_transpose<<<dim3(SEQ / 32, DHD / 32, BH), t32, 0, stream>>>(
                qkvq + 2 * DIM, QKV, cpart, vTq);
            // o = P @ vT  (fp8 in, bf16 out, causal K-truncation, pairing)
            gemm128pv_f8<<<dim3(2, SEQ / 128, BH), 256, 0, stream>>>(
                wbufq, vTq, ob);
            resid_ln<<<ROWS, 256, 0, stream>>>(
                hb, ob, ln_g + (size_t)ij * DIM, ln_b + (size_t)ij * DIM, hb, hq);
        }
        // FF — fp8
        gemm128_f8<<<dim3(FFD / 128, ROWS / 128, 1), 256, 0, stream>>>(
            hq, W1T8 + (size_t)i * DIM * FFD, DIM,
            b1 + (size_t)i * FFD, nullptr, ff1q, FFD, 1);
        gemm128_f8<<<dim3(DIM / 128, ROWS / 128, 1), 256, 0, stream>>>(
            ff1q, W2T8 + (size_t)i * FFD * DIM, FFD,
            b2 + (size_t)i * DIM, ob, nullptr, DIM, 0);
        resid_ln<<<ROWS, 256, 0, stream>>>(
            hb, ob, f_g + (size_t)i * DIM, f_b + (size_t)i * DIM, hb, hq);
    }

    // classifier in fp8: streaming lse partials + label pick
    gemm256_f8<<<dim3(NT2, ROWS / 256, 1), 512, 0, stream>>>(
        hq, WcT8, DIM, bcls, label, partials, picked);
    lse_merge<<<ROWS, 256, 0, stream>>>(partials, lsev);
    loss_k<<<1, 256, 0, stream>>>(lsev, picked, (float*)d_out);
}

// Round 21
// 1722.771 us; speedup vs baseline: 1.0241x; 1.0241x over previous
//
#include <hip/hip_runtime.h>
#include <hip/hip_bf16.h>

using u16 = unsigned short;
using u32 = unsigned int;
using u8  = unsigned char;
using u64 = unsigned long long;
using bf16x8 = __attribute__((ext_vector_type(8))) short;
using f32x4  = __attribute__((ext_vector_type(4))) float;
using l2v    = __attribute__((ext_vector_type(2))) long;

namespace {
constexpr int BB   = 4;
constexpr int SEQ  = 2048;
constexpr int DIM  = 768;
constexpr int NH   = 4;
constexpr int DHD  = 192;   // DIM / NH
constexpr int VOC  = 32000;
constexpr int NLAY = 3;
constexpr int FFD  = 1024;
constexpr int ROWS = BB * SEQ;      // 8192
constexpr int NT2  = VOC / 256;     // 125 classifier n-tiles
constexpr int QKV = 3 * DIM;        // 2304
constexpr int BH  = BB * NH;        // 16
}

__device__ __forceinline__ float b2f(u16 u) { return __uint_as_float(((u32)u) << 16); }
__device__ __forceinline__ u16 f2b(float f) {
    u32 x = __float_as_uint(f);
    return (u16)((x + 0x7fffu + ((x >> 16) & 1u)) >> 16);
}

// f32 -> OCP e4m3fn, RNE, saturating.
__device__ __forceinline__ u32 f2e4m3(float f) {
    float af = fabsf(f);
    u32 sgn = (__float_as_uint(f) >> 24) & 0x80u;
    if (!(af < 448.f)) return sgn | 0x7Eu;
    int e = (int)((__float_as_uint(af) >> 23) & 0xff) - 127;
    if (e < -6) e = -6;
    float sc = __uint_as_float((u32)(130 - e) << 23);   // 2^(3-e)
    int code = __float2int_rn(af * sc) + ((e + 6) << 3);
    return sgn | (u32)code;
}

__device__ __forceinline__ void gload16(const u16* g, u16* l) {
    __builtin_amdgcn_global_load_lds(
        (const __attribute__((address_space(1))) u32*)g,
        (__attribute__((address_space(3))) u32*)l, 16, 0, 0);
}
__device__ __forceinline__ void gload16b(const u8* g, u8* l) {
    __builtin_amdgcn_global_load_lds(
        (const __attribute__((address_space(1))) u32*)g,
        (__attribute__((address_space(3))) u32*)l, 16, 0, 0);
}

// phase boundary: counted vmcnt (never 0 in steady state) + raw barrier.
#define PHASE_END(N) do {                                        \
    __builtin_amdgcn_sched_barrier(0);                           \
    asm volatile("s_waitcnt vmcnt(" #N ")" ::: "memory");        \
    __builtin_amdgcn_s_barrier();                                \
    asm volatile("" ::: "memory");                               \
    __builtin_amdgcn_sched_barrier(0);                           \
} while (0)

__device__ __forceinline__ float block_sum256(float v, float* sb) {
    #pragma unroll
    for (int off = 32; off > 0; off >>= 1) v += __shfl_down(v, off, 64);
    int lane = threadIdx.x & 63, w = threadIdx.x >> 6;
    if (lane == 0) sb[w] = v;
    __syncthreads();
    float r = sb[0] + sb[1] + sb[2] + sb[3];
    __syncthreads();
    return r;
}

// ---------------------------------------------------------------------------
// 256x256 NT GEMM bf16, BK=64, counted-vmcnt 2-phase (round-6 structure).
// MODE 1 only: scores — TRIANGULAR grid (36 lower-tri tiles, z=16);
// mask/exp/colsum epilogue.
// ---------------------------------------------------------------------------
template<int MODE>
__global__ __launch_bounds__(512, 2)
void gemm256(const u16* __restrict__ A, long lda,
             const u16* __restrict__ Bt, long ldb,
             int M, int N, int K,
             u16* __restrict__ Cb, long ldc,
             int HH, long sAb, long sAh, long sBb, long sBh, long sCb, long sCh,
             const int* __restrict__ xtok, float* __restrict__ cpart)
{
    __shared__ __align__(16) u16 sA[2][256 * 64];
    __shared__ __align__(16) u16 sB[2][256 * 64];

    int t = threadIdx.x, w = t >> 6, lane = t & 63;
    int wr = w >> 2, wcn = w & 3;
    int lr = lane & 15, lg = lane >> 4, rsw = lr & 7;

    int z = blockIdx.z;
    int bz = z / HH, hz = z % HH;
    const u16* Ab = A + (size_t)bz * sAb + (size_t)hz * sAh;
    const u16* Bb = Bt + (size_t)bz * sBb + (size_t)hz * sBh;
    size_t Coff = (size_t)bz * sCb + (size_t)hz * sCh;

    int bx = blockIdx.x, by = blockIdx.y;
    {
        // triangular map: tix -> (by, bx) with bx <= by, by in [0,8)
        int tix = blockIdx.x;
        by = 7;
        while (by * (by + 1) / 2 > tix) by--;
        bx = tix - by * (by + 1) / 2;
    }
    int m0 = by * 256, n0 = bx * 256;

    int srow = lane >> 3;
    int scol = ((lane & 7) ^ srow) * 8;

    f32x4 acc[8][4];
    #pragma unroll
    for (int i = 0; i < 8; i++)
        #pragma unroll
        for (int j = 0; j < 4; j++) acc[i][j] = (f32x4){0.f, 0.f, 0.f, 0.f};

    auto stageA = [&](int buf, int k0) {
        #pragma unroll
        for (int r = 0; r < 4; r++) {
            int rb = r * 64 + w * 8;
            gload16(Ab + (size_t)(m0 + rb + srow) * lda + k0 + scol,
                    &sA[buf][rb * 64]);
        }
    };
    auto stageB = [&](int buf, int k0, int h) {
        #pragma unroll
        for (int j = 0; j < 2; j++) {
            int rb = (j * 2 + (w >> 2)) * 64 + h * 32 + (w & 3) * 8;
            gload16(Bb + (size_t)(n0 + rb + srow) * ldb + k0 + scol,
                    &sB[buf][rb * 64]);
        }
    };

    {
        int nt = K >> 6;
        stageA(0, 0); stageB(0, 0, 0); stageB(0, 0, 1);
        PHASE_END(0);

        for (int kt = 0; kt < nt; ++kt) {
            int cur = kt & 1;
            int kn = (kt + 1) << 6;
            bool st = (kt + 1 < nt);
            bf16x8 aa[2][8], bb[2][2];
            #pragma unroll
            for (int kx = 0; kx < 2; kx++) {
                int jsw = ((kx * 4 + lg) ^ rsw) * 8;
                #pragma unroll
                for (int mi = 0; mi < 8; mi++)
                    aa[kx][mi] = *(const bf16x8*)&sA[cur][(wr * 128 + mi * 16 + lr) * 64 + jsw];
                #pragma unroll
                for (int ni = 0; ni < 2; ni++)
                    bb[kx][ni] = *(const bf16x8*)&sB[cur][(wcn * 64 + ni * 16 + lr) * 64 + jsw];
            }
            if (st) { stageA(cur ^ 1, kn); stageB(cur ^ 1, kn, 0); }
            __builtin_amdgcn_s_setprio(1);
            #pragma unroll
            for (int kx = 0; kx < 2; kx++)
                #pragma unroll
                for (int mi = 0; mi < 8; mi++)
                    #pragma unroll
                    for (int ni = 0; ni < 2; ni++)
                        acc[mi][ni] = __builtin_amdgcn_mfma_f32_16x16x32_bf16(
                            aa[kx][mi], bb[kx][ni], acc[mi][ni], 0, 0, 0);
            __builtin_amdgcn_s_setprio(0);
            if (st) PHASE_END(6); else PHASE_END(0);

            bf16x8 bc[2][2];
            #pragma unroll
            for (int kx = 0; kx < 2; kx++) {
                int jsw = ((kx * 4 + lg) ^ rsw) * 8;
                #pragma unroll
                for (int ni = 0; ni < 2; ni++)
                    bc[kx][ni] = *(const bf16x8*)&sB[cur][(wcn * 64 + (ni + 2) * 16 + lr) * 64 + jsw];
            }
            if (st) stageB(cur ^ 1, kn, 1);
            __builtin_amdgcn_s_setprio(1);
            #pragma unroll
            for (int kx = 0; kx < 2; kx++)
                #pragma unroll
                for (int mi = 0; mi < 8; mi++)
                    #pragma unroll
                    for (int ni = 0; ni < 2; ni++)
                        acc[mi][ni + 2] = __builtin_amdgcn_mfma_f32_16x16x32_bf16(
                            aa[kx][mi], bc[kx][ni], acc[mi][ni + 2], 0, 0, 0);
            __builtin_amdgcn_s_setprio(0);
            if (st) PHASE_END(2); else PHASE_END(0);
        }
    }

    // MODE 1 epilogue: P = exp(masked(score/20)); masked -> exp(-30);
    // per-64-row colsum partials
    {
        const int* xb = xtok + (size_t)bz * SEQ;
        float cs[2][4] = {{0.f,0.f,0.f,0.f},{0.f,0.f,0.f,0.f}};
        #pragma unroll
        for (int mi = 0; mi < 8; mi++)
            #pragma unroll
            for (int j = 0; j < 4; j++) {
                int grow = m0 + wr * 128 + mi * 16 + lg * 4 + j;
                int xz = xb[grow];
                #pragma unroll
                for (int ni = 0; ni < 4; ni++) {
                    int gcol = n0 + wcn * 64 + ni * 16 + lr;
                    float v = acc[mi][ni][j] * 0.05f;
                    if (gcol > grow || xz == 0) v = -30.f;
                    float e = __expf(v);
                    Cb[Coff + (size_t)grow * ldc + gcol] = f2b(e);
                    cs[mi >> 2][ni] += e;
                }
            }
        #pragma unroll
        for (int h = 0; h < 2; h++)
            #pragma unroll
            for (int ni = 0; ni < 4; ni++) {
                float c = cs[h][ni];
                c += __shfl_xor(c, 16, 64);
                c += __shfl_xor(c, 32, 64);
                if (lg == 0) {
                    int p = (m0 >> 6) + wr * 2 + h;
                    cpart[((size_t)p * BH + z) * SEQ + n0 + wcn * 64 + ni * 16 + lr] = c;
                }
            }
    }
}

// ---------------------------------------------------------------------------
// Classifier GEMM in fp8-e4m3 (round-16 verified): 256x256, BK=128,
// counted-vmcnt 2-phase, b128 k-permutation reads (conflict-free).
// A is h*4 in fp8, B is W*16 in fp8 -> acc/64 in epilogue.
// ---------------------------------------------------------------------------
__global__ __launch_bounds__(512, 2)
void gemm256_f8(const u8* __restrict__ Aq, const u8* __restrict__ Bq, int K,
                const float* __restrict__ bias,
                const int* __restrict__ label,
                float* __restrict__ partials, float* __restrict__ picked)
{
    __shared__ __align__(16) u8 sA8[2][256 * 128];
    __shared__ __align__(16) u8 sB8[2][2][128 * 128];

    int t = threadIdx.x, w = t >> 6, lane = t & 63;
    int wr = w >> 2, wcn = w & 3;
    int lr = lane & 15, lg = lane >> 4;
    int rx = lr & 7;

    int bx = blockIdx.x, by = blockIdx.y;
    {
        int pid = by * gridDim.x + bx;
        int xcd = pid & 7, s = pid >> 3;
        bx = s >> 2;
        by = xcd * 4 + (s & 3);
    }
    int m0 = by * 256, n0 = bx * 256;

    int srow8 = lane >> 3;
    int scol8 = ((lane & 7) ^ srow8) * 16;   // pre-swizzled source (chunk^row&7)

    f32x4 acc[8][4];
    #pragma unroll
    for (int i = 0; i < 8; i++)
        #pragma unroll
        for (int j = 0; j < 4; j++) acc[i][j] = (f32x4){0.f, 0.f, 0.f, 0.f};

    auto stageA = [&](int buf, int k0) {
        #pragma unroll
        for (int i = 0; i < 4; i++) {
            int rb = i * 64 + w * 8;
            gload16b(Aq + (size_t)(m0 + rb + srow8) * DIM + k0 + scol8,
                     &sA8[buf][rb * 128]);
        }
    };
    auto stageB = [&](int buf, int k0, int h) {
        #pragma unroll
        for (int j = 0; j < 2; j++) {
            int rh = j * 64 + w * 8;
            int rbase = (rh >> 5) * 64 + h * 32 + (rh & 31);
            gload16b(Bq + (size_t)(n0 + rbase + srow8) * DIM + k0 + scol8,
                     &sB8[buf][h][rh * 128]);
        }
    };

    int nt = K >> 7;   // BK = 128
    stageA(0, 0); stageB(0, 0, 0); stageB(0, 0, 1);
    PHASE_END(0);

    for (int kt = 0; kt < nt; ++kt) {
        int cur = kt & 1;
        int kn = (kt + 1) << 7;
        bool st = (kt + 1 < nt);
        // ---------- phase 0: ni{0,1} ----------
        l2v aa[2][8], bb[2][2];
        #pragma unroll
        for (int h = 0; h < 2; h++) {
            int off = ((2 * lg + h) ^ rx) * 16;
            #pragma unroll
            for (int mi = 0; mi < 8; mi++)
                aa[h][mi] = *(const l2v*)&sA8[cur][(wr * 128 + mi * 16 + lr) * 128 + off];
            #pragma unroll
            for (int ni = 0; ni < 2; ni++)
                bb[h][ni] = *(const l2v*)&sB8[cur][0][(wcn * 32 + ni * 16 + lr) * 128 + off];
        }
        if (st) { stageA(cur ^ 1, kn); stageB(cur ^ 1, kn, 0); }
        __builtin_amdgcn_s_setprio(1);
        #pragma unroll
        for (int h = 0; h < 2; h++)
            #pragma unroll
            for (int e = 0; e < 2; e++)
                #pragma unroll
                for (int mi = 0; mi < 8; mi++)
                    #pragma unroll
                    for (int ni = 0; ni < 2; ni++)
                        acc[mi][ni] = __builtin_amdgcn_mfma_f32_16x16x32_fp8_fp8(
                            aa[h][mi][e], bb[h][ni][e], acc[mi][ni], 0, 0, 0);
        __builtin_amdgcn_s_setprio(0);
        if (st) PHASE_END(6); else PHASE_END(0);
        // ---------- phase 1: ni{2,3} ----------
        l2v bc[2][2];
        #pragma unroll
        for (int h = 0; h < 2; h++) {
            int off = ((2 * lg + h) ^ rx) * 16;
            #pragma unroll
            for (int ni = 0; ni < 2; ni++)
                bc[h][ni] = *(const l2v*)&sB8[cur][1][(wcn * 32 + ni * 16 + lr) * 128 + off];
        }
        if (st) stageB(cur ^ 1, kn, 1);
        __builtin_amdgcn_s_setprio(1);
        #pragma unroll
        for (int h = 0; h < 2; h++)
            #pragma unroll
            for (int e = 0; e < 2; e++)
                #pragma unroll
                for (int mi = 0; mi < 8; mi++)
                    #pragma unroll
                    for (int ni = 0; ni < 2; ni++)
                        acc[mi][ni + 2] = __builtin_amdgcn_mfma_f32_16x16x32_fp8_fp8(
                            aa[h][mi][e], bc[h][ni][e], acc[mi][ni + 2], 0, 0, 0);
        __builtin_amdgcn_s_setprio(0);
        if (st) PHASE_END(2); else PHASE_END(0);
    }

    // epilogue: unscale + bias, label pick, per-row (max,sumexp) partials
    #pragma unroll
    for (int mi = 0; mi < 8; mi++)
        #pragma unroll
        for (int ni = 0; ni < 4; ni++) {
            int gcol = n0 + wcn * 64 + ni * 16 + lr;
            float bcol = bias[gcol];
            #pragma unroll
            for (int j = 0; j < 4; j++)
                acc[mi][ni][j] = acc[mi][ni][j] * (1.f / 64.f) + bcol;
        }
    #pragma unroll
    for (int mi = 0; mi < 8; mi++)
        #pragma unroll
        for (int j = 0; j < 4; j++) {
            int grow = m0 + wr * 128 + mi * 16 + lg * 4 + j;
            int lab = label[grow];
            #pragma unroll
            for (int ni = 0; ni < 4; ni++) {
                int gcol = n0 + wcn * 64 + ni * 16 + lr;
                if (lab == gcol) picked[grow] = acc[mi][ni][j];
            }
        }
    float* red = (float*)sA8;  // [256 rows][4 wcn][2]
    #pragma unroll
    for (int mi = 0; mi < 8; mi++)
        #pragma unroll
        for (int j = 0; j < 4; j++) {
            float mx = -1e30f;
            #pragma unroll
            for (int ni = 0; ni < 4; ni++) mx = fmaxf(mx, acc[mi][ni][j]);
            #pragma unroll
            for (int off = 1; off < 16; off <<= 1)
                mx = fmaxf(mx, __shfl_xor(mx, off, 64));
            float ss = 0.f;
            #pragma unroll
            for (int ni = 0; ni < 4; ni++) ss += __expf(acc[mi][ni][j] - mx);
            #pragma unroll
            for (int off = 1; off < 16; off <<= 1) ss += __shfl_xor(ss, off, 64);
            if (lr == 0) {
                int rloc = wr * 128 + mi * 16 + lg * 4 + j;
                red[rloc * 8 + wcn * 2 + 0] = mx;
                red[rloc * 8 + wcn * 2 + 1] = ss;
            }
        }
    __syncthreads();
    if (t < 256) {
        float Mv = -1e30f;
        #pragma unroll
        for (int q = 0; q < 4; q++) Mv = fmaxf(Mv, red[t * 8 + q * 2]);
        float Sv = 0.f;
        #pragma unroll
        for (int q = 0; q < 4; q++)
            Sv += red[t * 8 + q * 2 + 1] * __expf(red[t * 8 + q * 2] - Mv);
        size_t row = (size_t)(m0 + t);
        partials[(row * NT2 + bx) * 2 + 0] = Mv;
        partials[(row * NT2 + bx) * 2 + 1] = Sv;
    }
}

// ---------------------------------------------------------------------------
// 128x128 NT GEMM fp8 (QKV / FF1 / FF2): BK=128, counted-vmcnt 2-phase,
// b128 k-perm reads. A = act*4 fp8 (row stride K), B = W*16 fp8 [N][K]
// -> acc/64. Epilogue: +bias, optional relu; bf16 (Cb) and/or fp8*4 (Cq).
// XCD-banded remap (gridDim.y == 64).
// ---------------------------------------------------------------------------
__global__ __launch_bounds__(256)
void gemm128_f8(const u8* __restrict__ Aq, const u8* __restrict__ Bq,
                int K,
                const float* __restrict__ bias,
                u16* __restrict__ Cb, u8* __restrict__ Cq, long ldc, int relu)
{
    __shared__ __align__(16) u8 sA8[2][128 * 128];
    __shared__ __align__(16) u8 sB8[2][2][64 * 128];

    int t = threadIdx.x, w = t >> 6, lane = t & 63;
    int wr = w >> 1, wc = w & 1;
    int lr = lane & 15, lg = lane >> 4;
    int rx = lr & 7;

    int bx = blockIdx.x, by = blockIdx.y;
    {
        int pid = by * gridDim.x + bx;
        int xcd = pid & 7, s = pid >> 3;
        bx = s >> 3;
        by = xcd * 8 + (s & 7);
    }
    int m0 = by * 128, n0 = bx * 128;

    int srow8 = lane >> 3;
    int scol8 = ((lane & 7) ^ srow8) * 16;

    f32x4 acc[4][4];
    #pragma unroll
    for (int i = 0; i < 4; i++)
        #pragma unroll
        for (int j = 0; j < 4; j++) acc[i][j] = (f32x4){0.f, 0.f, 0.f, 0.f};

    auto stageA = [&](int buf, int k0) {
        #pragma unroll
        for (int i = 0; i < 4; i++) {
            int rb = i * 32 + w * 8;
            gload16b(Aq + (size_t)(m0 + rb + srow8) * K + k0 + scol8,
                     &sA8[buf][rb * 128]);
        }
    };
    auto stageB = [&](int buf, int k0, int h) {
        #pragma unroll
        for (int j = 0; j < 2; j++) {
            int rh = j * 32 + w * 8;               // storage row (uniform)
            int rbase = j * 64 + h * 32 + w * 8;   // tile row base
            gload16b(Bq + (size_t)(n0 + rbase + srow8) * K + k0 + scol8,
                     &sB8[buf][h][rh * 128]);
        }
    };

    int nt = K >> 7;   // BK = 128 (K = 768 or 1024)
    stageA(0, 0); stageB(0, 0, 0); stageB(0, 0, 1);
    PHASE_END(0);

    for (int kt = 0; kt < nt; ++kt) {
        int cur = kt & 1;
        int kn = (kt + 1) << 7;
        bool st = (kt + 1 < nt);
        l2v aa[2][4], bb[2][2];
        #pragma unroll
        for (int h = 0; h < 2; h++) {
            int off = ((2 * lg + h) ^ rx) * 16;
            #pragma unroll
            for (int mi = 0; mi < 4; mi++)
                aa[h][mi] = *(const l2v*)&sA8[cur][(wr * 64 + mi * 16 + lr) * 128 + off];
            #pragma unroll
            for (int ni = 0; ni < 2; ni++)
                bb[h][ni] = *(const l2v*)&sB8[cur][0][(wc * 32 + ni * 16 + lr) * 128 + off];
        }
        if (st) { stageA(cur ^ 1, kn); stageB(cur ^ 1, kn, 0); }
        __builtin_amdgcn_s_setprio(1);
        #pragma unroll
        for (int h = 0; h < 2; h++)
            #pragma unroll
            for (int e = 0; e < 2; e++)
                #pragma unroll
                for (int mi = 0; mi < 4; mi++)
                    #pragma unroll
                    for (int ni = 0; ni < 2; ni++)
                        acc[mi][ni] = __builtin_amdgcn_mfma_f32_16x16x32_fp8_fp8(
                            aa[h][mi][e], bb[h][ni][e], acc[mi][ni], 0, 0, 0);
        __builtin_amdgcn_s_setprio(0);
        if (st) PHASE_END(6); else PHASE_END(0);

        l2v bc[2][2];
        #pragma unroll
        for (int h = 0; h < 2; h++) {
            int off = ((2 * lg + h) ^ rx) * 16;
            #pragma unroll
            for (int ni = 0; ni < 2; ni++)
                bc[h][ni] = *(const l2v*)&sB8[cur][1][(wc * 32 + ni * 16 + lr) * 128 + off];
        }
        if (st) stageB(cur ^ 1, kn, 1);
        __builtin_amdgcn_s_setprio(1);
        #pragma unroll
        for (int h = 0; h < 2; h++)
            #pragma unroll
            for (int e = 0; e < 2; e++)
                #pragma unroll
                for (int mi = 0; mi < 4; mi++)
                    #pragma unroll
                    for (int ni = 0; ni < 2; ni++)
                        acc[mi][ni + 2] = __builtin_amdgcn_mfma_f32_16x16x32_fp8_fp8(
                            aa[h][mi][e], bc[h][ni][e], acc[mi][ni + 2], 0, 0, 0);
        __builtin_amdgcn_s_setprio(0);
        if (st) PHASE_END(2); else PHASE_END(0);
    }

    #pragma unroll
    for (int mi = 0; mi < 4; mi++)
        #pragma unroll
        for (int ni = 0; ni < 4; ni++)
            #pragma unroll
            for (int j = 0; j < 4; j++) {
                int grow = m0 + wr * 64 + mi * 16 + lg * 4 + j;
                int gcol = n0 + wc * 64 + ni * 16 + lr;
                float v = acc[mi][ni][j] * (1.f / 64.f) + bias[gcol];
                if (relu) v = fmaxf(v, 0.f);
                size_t ci = (size_t)grow * ldc + gcol;
                if (Cb) Cb[ci] = f2b(v);
                if (Cq) Cq[ci] = (u8)f2e4m3(v * 4.f);
            }
}

// ---------------------------------------------------------------------------
// 128x128 NT GEMM bf16, counted-vmcnt 2-phase. MODE 3: PV — z-batched,
// N=192 via clamp, causal K-truncation, bf16 out, balanced by-pairing.
// ---------------------------------------------------------------------------
template<int MODE>
__global__ __launch_bounds__(256)
void gemm128(const u16* __restrict__ A, long lda,
             const u16* __restrict__ Bt, long ldb,
             int N, int K,
             const float* __restrict__ bias,
             u16* __restrict__ Cb, long ldc, int relu,
             int HH, long sAb, long sAh, long sBb, long sBh, long sCb, long sCh)
{
    __shared__ __align__(16) u16 sA[2][128 * 64];
    __shared__ __align__(16) u16 sB[2][128 * 64];

    int z = blockIdx.z, bz = z / HH, hz = z % HH;
    const u16* Ab = A + (size_t)bz * sAb + (size_t)hz * sAh;
    const u16* Bb = Bt + (size_t)bz * sBb + (size_t)hz * sBh;
    size_t Coff = (size_t)bz * sCb + (size_t)hz * sCh;

    int bx = blockIdx.x, by = blockIdx.y;
    if (MODE == 3) {
        by = (by & 1) ? (15 - (by >> 1)) : (by >> 1);
    }
    int m0 = by * 128, n0 = bx * 128;

    int t = threadIdx.x, w = t >> 6, lane = t & 63;
    int wr = w >> 1, wc = w & 1, lr = lane & 15, lg = lane >> 4, rsw = lr & 7;
    int srow = lane >> 3, scol = ((lane & 7) ^ srow) * 8;

    f32x4 acc[4][4];
    #pragma unroll
    for (int i = 0; i < 4; i++)
        #pragma unroll
        for (int j = 0; j < 4; j++) acc[i][j] = (f32x4){0.f, 0.f, 0.f, 0.f};

    auto stageA = [&](int buf, int k0) {
        #pragma unroll
        for (int i = 0; i < 4; i++) {
            int rb = (w * 4 + i) * 8;
            gload16(Ab + (size_t)(m0 + rb + srow) * lda + k0 + scol,
                    &sA[buf][rb * 64]);
        }
    };
    auto stageB = [&](int buf, int k0, int h) {
        #pragma unroll
        for (int j = 0; j < 2; j++) {
            int rb = j * 64 + h * 32 + w * 8;
            int row = n0 + rb + srow;
            if (MODE == 3) { if (row > N - 1) row = N - 1; }
            gload16(Bb + (size_t)row * ldb + k0 + scol, &sB[buf][rb * 64]);
        }
    };

    int nt = K >> 6;
    if (MODE == 3) {
        int ntE = (by + 1) * 2;
        if (ntE < nt) nt = ntE;
    }

    stageA(0, 0); stageB(0, 0, 0); stageB(0, 0, 1);
    PHASE_END(0);

    for (int kt = 0; kt < nt; ++kt) {
        int cur = kt & 1;
        int kn = (kt + 1) << 6;
        bool st = (kt + 1 < nt);
        bf16x8 aa[2][4], bb[2][2];
        #pragma unroll
        for (int kx = 0; kx < 2; kx++) {
            int jsw = ((kx * 4 + lg) ^ rsw) * 8;
            #pragma unroll
            for (int mi = 0; mi < 4; mi++)
                aa[kx][mi] = *(const bf16x8*)&sA[cur][(wr * 64 + mi * 16 + lr) * 64 + jsw];
            #pragma unroll
            for (int ni = 0; ni < 2; ni++)
                bb[kx][ni] = *(const bf16x8*)&sB[cur][(wc * 64 + ni * 16 + lr) * 64 + jsw];
        }
        if (st) { stageA(cur ^ 1, kn); stageB(cur ^ 1, kn, 0); }
        __builtin_amdgcn_s_setprio(1);
        #pragma unroll
        for (int kx = 0; kx < 2; kx++)
            #pragma unroll
            for (int mi = 0; mi < 4; mi++)
                #pragma unroll
                for (int ni = 0; ni < 2; ni++)
                    acc[mi][ni] = __builtin_amdgcn_mfma_f32_16x16x32_bf16(
                        aa[kx][mi], bb[kx][ni], acc[mi][ni], 0, 0, 0);
        __builtin_amdgcn_s_setprio(0);
        if (st) PHASE_END(6); else PHASE_END(0);

        bf16x8 bc[2][2];
        #pragma unroll
        for (int kx = 0; kx < 2; kx++) {
            int jsw = ((kx * 4 + lg) ^ rsw) * 8;
            #pragma unroll
            for (int ni = 0; ni < 2; ni++)
                bc[kx][ni] = *(const bf16x8*)&sB[cur][(wc * 64 + (ni + 2) * 16 + lr) * 64 + jsw];
        }
        if (st) stageB(cur ^ 1, kn, 1);
        __builtin_amdgcn_s_setprio(1);
        #pragma unroll
        for (int kx = 0; kx < 2; kx++)
            #pragma unroll
            for (int mi = 0; mi < 4; mi++)
                #pragma unroll
                for (int ni = 0; ni < 2; ni++)
                    acc[mi][ni + 2] = __builtin_amdgcn_mfma_f32_16x16x32_bf16(
                        aa[kx][mi], bc[kx][ni], acc[mi][ni + 2], 0, 0, 0);
        __builtin_amdgcn_s_setprio(0);
        if (st) PHASE_END(2); else PHASE_END(0);
    }

    #pragma unroll
    for (int mi = 0; mi < 4; mi++)
        #pragma unroll
        for (int ni = 0; ni < 4; ni++)
            #pragma unroll
            for (int j = 0; j < 4; j++) {
                int grow = m0 + wr * 64 + mi * 16 + lg * 4 + j;
                int gcol = n0 + wc * 64 + ni * 16 + lr;
                if (gcol < N)
                    Cb[Coff + (size_t)grow * ldc + gcol] = f2b(acc[mi][ni][j]);
            }
}

// ---------------------------------------------------------------------------
__global__ __launch_bounds__(256)
void embed_k(const int* __restrict__ x, const float* __restrict__ tok,
             const float* __restrict__ pos, u16* __restrict__ hb, u8* __restrict__ hq)
{
    int row = blockIdx.x, t = threadIdx.x;
    int token = x[row];
    int s = row & (SEQ - 1);
    size_t base = (size_t)row * DIM;
    #pragma unroll
    for (int e = 0; e < 3; e++) {
        int d = t + e * 256;
        float v = tok[(size_t)token * DIM + d] + pos[(size_t)s * DIM + d];
        hb[base + d] = f2b(v);
        hq[base + d] = (u8)f2e4m3(v * 4.f);
    }
}

// h' = LN(res + add), bf16 in, bf16 + fp8(x4) out, f32 stats. In-place safe.
__global__ __launch_bounds__(256)
void resid_ln(const u16* __restrict__ res, const u16* __restrict__ add,
              const float* __restrict__ g, const float* __restrict__ b,
              u16* __restrict__ out, u8* __restrict__ outq)
{
    __shared__ float sb[4];
    int row = blockIdx.x, t = threadIdx.x;
    size_t base = (size_t)row * DIM;
    float x0 = 0.f, x1 = 0.f, x2 = 0.f, x3 = 0.f;
    if (t < 192) {
        ushort4 r4 = *(const ushort4*)&res[base + t * 4];
        ushort4 a4 = *(const ushort4*)&add[base + t * 4];
        x0 = b2f(r4.x) + b2f(a4.x);
        x1 = b2f(r4.y) + b2f(a4.y);
        x2 = b2f(r4.z) + b2f(a4.z);
        x3 = b2f(r4.w) + b2f(a4.w);
    }
    float mean = block_sum256(x0 + x1 + x2 + x3, sb) * (1.f / DIM);
    float d0 = x0 - mean, d1 = x1 - mean, d2 = x2 - mean, d3 = x3 - mean;
    float var = block_sum256(t < 192 ? d0*d0 + d1*d1 + d2*d2 + d3*d3 : 0.f, sb) * (1.f / DIM);
    float rs = rsqrtf(var + 1e-5f);
    if (t < 192) {
        float4 gv = *(const float4*)&g[t * 4];
        float4 bv = *(const float4*)&b[t * 4];
        float y0 = d0 * rs * gv.x + bv.x, y1 = d1 * rs * gv.y + bv.y;
        float y2 = d2 * rs * gv.z + bv.z, y3 = d3 * rs * gv.w + bv.w;
        ushort4 ob = {f2b(y0), f2b(y1), f2b(y2), f2b(y3)};
        *(ushort4*)&out[base + t * 4] = ob;
        uchar4 oq = {(u8)f2e4m3(y0 * 4.f), (u8)f2e4m3(y1 * 4.f),
                     (u8)f2e4m3(y2 * 4.f), (u8)f2e4m3(y3 * 4.f)};
        *(uchar4*)&outq[base + t * 4] = oq;
    }
}

// v rows at stride ldv (bf16) -> vT [B*H][DH][S], scaled by 1/colsum(s).
__global__ void v_transpose(const u16* __restrict__ v, long ldv,
                            const float* __restrict__ cpart, u16* __restrict__ vT)
{
    __shared__ u16 tile[32][33];
    int z = blockIdx.z;
    int b = z >> 2, h = z & 3;
    int s0 = blockIdx.x * 32, d0 = blockIdx.y * 32;
    int tx = threadIdx.x, ty = threadIdx.y;
    #pragma unroll
    for (int i = 0; i < 4; i++)
        tile[ty + i * 8][tx] = v[((size_t)b * SEQ + s0 + ty + i * 8) * ldv + h * DHD + d0 + tx];
    int scol = s0 + tx;
    int pmin = (scol >> 8) * 4;
    float sv = 0.f;
    for (int p = pmin; p < 32; p++) sv += cpart[((size_t)p * BH + z) * SEQ + scol];
    float inv = 1.f / sv;
    __syncthreads();
    #pragma unroll
    for (int i = 0; i < 4; i++)
        vT[((size_t)z * DHD + d0 + ty + i * 8) * SEQ + scol] =
            f2b(b2f(tile[tx][ty + i * 8]) * inv);
}

// W [K][N] f32 -> Wt [N][K] bf16, z-batched (src/dst strides in elements)
__global__ void wt_cvt_z(const float* __restrict__ src0, long sSrc,
                         u16* __restrict__ dst0, long sDst, int K, int N)
{
    __shared__ float tile[32][33];
    const float* src = src0 + (size_t)blockIdx.z * sSrc;
    u16* dst = dst0 + (size_t)blockIdx.z * sDst;
    int n0 = blockIdx.x * 32, k0 = blockIdx.y * 32;
    int tx = threadIdx.x, ty = threadIdx.y;
    #pragma unroll
    for (int i = 0; i < 4; i++)
        tile[ty + i * 8][tx] = src[(size_t)(k0 + ty + i * 8) * N + n0 + tx];
    __syncthreads();
    #pragma unroll
    for (int i = 0; i < 4; i++)
        dst[(size_t)(n0 + ty + i * 8) * K + k0 + tx] = f2b(tile[tx][ty + i * 8]);
}

// W [K][N] f32 -> Wt [N][K] fp8 (x16), z-batched
__global__ void wt_cvt8_z(const float* __restrict__ src0, long sSrc,
                          u8* __restrict__ dst0, long sDst, int K, int N)
{
    __shared__ float tile[32][33];
    const float* src = src0 + (size_t)blockIdx.z * sSrc;
    u8* dst = dst0 + (size_t)blockIdx.z * sDst;
    int n0 = blockIdx.x * 32, k0 = blockIdx.y * 32;
    int tx = threadIdx.x, ty = threadIdx.y;
    #pragma unroll
    for (int i = 0; i < 4; i++)
        tile[ty + i * 8][tx] = src[(size_t)(k0 + ty + i * 8) * N + n0 + tx];
    __syncthreads();
    #pragma unroll
    for (int i = 0; i < 4; i++)
        dst[(size_t)(n0 + ty + i * 8) * K + k0 + tx] =
            (u8)f2e4m3(tile[tx][ty + i * 8] * 16.f);
}

__global__ __launch_bounds__(256)
void bias_cat(const float* __restrict__ bq, const float* __restrict__ bk,
              const float* __restrict__ bv, float* __restrict__ dst)
{
    int ij = blockIdx.x, t = threadIdx.x;
    #pragma unroll
    for (int e = 0; e < 3; e++) {
        int d = t + e * 256;
        dst[(size_t)ij * QKV + d]            = bq[(size_t)ij * DIM + d];
        dst[(size_t)ij * QKV + DIM + d]      = bk[(size_t)ij * DIM + d];
        dst[(size_t)ij * QKV + 2 * DIM + d]  = bv[(size_t)ij * DIM + d];
    }
}

__global__ __launch_bounds__(256)
void lse_merge(const float* __restrict__ partials, float* __restrict__ lse)
{
    __shared__ float sm[4], ssum[4];
    int row = blockIdx.x, t = threadIdx.x;
    float m = -1e30f, s = 0.f;
    if (t < NT2) {
        const float* p = partials + ((size_t)row * NT2 + t) * 2;
        m = p[0]; s = p[1];
    }
    #pragma unroll
    for (int off = 1; off < 64; off <<= 1) {
        float om = __shfl_xor(m, off, 64), os = __shfl_xor(s, off, 64);
        float M = fmaxf(m, om);
        s = s * __expf(m - M) + os * __expf(om - M);
        m = M;
    }
    int lane = t & 63, w = t >> 6;
    if (lane == 0) { sm[w] = m; ssum[w] = s; }
    __syncthreads();
    if (t == 0) {
        float M = fmaxf(fmaxf(sm[0], sm[1]), fmaxf(sm[2], sm[3]));
        float S = ssum[0] * __expf(sm[0] - M) + ssum[1] * __expf(sm[1] - M) +
                  ssum[2] * __expf(sm[2] - M) + ssum[3] * __expf(sm[3] - M);
        lse[row] = M + __logf(S);
    }
}

__global__ __launch_bounds__(256)
void loss_k(const float* __restrict__ lse, const float* __restrict__ picked,
            float* __restrict__ out)
{
    __shared__ float sb[4];
    int t = threadIdx.x;
    float a = 0.f;
    for (int r = t; r < ROWS; r += 256) a += lse[r] - picked[r];
    float tot = block_sum256(a, sb);
    if (t == 0) out[0] = tot / (float)ROWS;
}

// ---------------------------------------------------------------------------
extern "C" void kernel_launch(void* const* d_in, const int* in_sizes, int n_in,
                              void* d_out, int out_size, void* d_ws, size_t ws_size,
                              hipStream_t stream)
{
    (void)in_sizes; (void)n_in; (void)out_size; (void)ws_size;
    const int*   x     = (const int*)d_in[0];
    const int*   label = (const int*)d_in[1];
    const float* tok   = (const float*)d_in[2];
    const float* pos   = (const float*)d_in[3];
    const float* Wq    = (const float*)d_in[4];
    const float* bq    = (const float*)d_in[5];
    const float* Wk    = (const float*)d_in[6];
    const float* bk    = (const float*)d_in[7];
    const float* Wv    = (const float*)d_in[8];
    const float* bv    = (const float*)d_in[9];
    const float* ln_g  = (const float*)d_in[10];
    const float* ln_b  = (const float*)d_in[11];
    const float* W1    = (const float*)d_in[12];
    const float* b1    = (const float*)d_in[13];
    const float* W2    = (const float*)d_in[14];
    const float* b2    = (const float*)d_in[15];
    const float* f_g   = (const float*)d_in[16];
    const float* f_b   = (const float*)d_in[17];
    const float* Wcls  = (const float*)d_in[18];
    const float* bcls  = (const float*)d_in[19];

    char* p = (char*)d_ws;
    auto alloc = [&](size_t bytes) -> char* {
        char* r = p;
        p += (bytes + 255) & ~(size_t)255;
        return r;
    };
    u16* hb     = (u16*)alloc((size_t)ROWS * DIM * 2);   // h stream (bf16)
    u8*  hq     = (u8*)alloc((size_t)ROWS * DIM);        // h stream (fp8 x4)
    u16* ob     = (u16*)alloc((size_t)ROWS * DIM * 2);   // block output (bf16)
    u16* qkvb   = (u16*)alloc((size_t)ROWS * QKV * 2);
    u16* vTb    = (u16*)alloc((size_t)BH * DHD * SEQ * 2);
    u8*  ff1q   = (u8*)alloc((size_t)ROWS * FFD);        // FF1 out (fp8 x4)
    u16* wbuf   = (u16*)alloc((size_t)BH * SEQ * SEQ * 2);
    u8*  WqkvT8 = (u8*)alloc((size_t)6 * QKV * DIM);
    u8*  W1T8   = (u8*)alloc((size_t)NLAY * DIM * FFD);
    u8*  W2T8   = (u8*)alloc((size_t)NLAY * FFD * DIM);
    u8*  WcT8   = (u8*)alloc((size_t)DIM * VOC);
    float* bqkv = (float*)alloc((size_t)6 * QKV * 4);
    float* cpart= (float*)alloc((size_t)32 * BH * SEQ * 4);
    float* partials = (float*)alloc((size_t)ROWS * NT2 * 2 * 4);
    float* picked   = (float*)alloc((size_t)ROWS * 4);
    float* lsev     = (float*)alloc((size_t)ROWS * 4);

    dim3 t32(32, 8, 1);
    // batched fp8 weight conversions
    wt_cvt8_z<<<dim3(DIM / 32, DIM / 32, 6), t32, 0, stream>>>(
        Wq, (long)DIM * DIM, WqkvT8, (long)QKV * DIM, DIM, DIM);
    wt_cvt8_z<<<dim3(DIM / 32, DIM / 32, 6), t32, 0, stream>>>(
        Wk, (long)DIM * DIM, WqkvT8 + (size_t)DIM * DIM, (long)QKV * DIM, DIM, DIM);
    wt_cvt8_z<<<dim3(DIM / 32, DIM / 32, 6), t32, 0, stream>>>(
        Wv, (long)DIM * DIM, WqkvT8 + (size_t)2 * DIM * DIM, (long)QKV * DIM, DIM, DIM);
    wt_cvt8_z<<<dim3(FFD / 32, DIM / 32, NLAY), t32, 0, stream>>>(
        W1, (long)DIM * FFD, W1T8, (long)DIM * FFD, DIM, FFD);
    wt_cvt8_z<<<dim3(DIM / 32, FFD / 32, NLAY), t32, 0, stream>>>(
        W2, (long)FFD * DIM, W2T8, (long)FFD * DIM, FFD, DIM);
    wt_cvt8_z<<<dim3(VOC / 32, DIM / 32, 1), t32, 0, stream>>>(
        Wcls, 0L, WcT8, 0L, DIM, VOC);
    bias_cat<<<6, 256, 0, stream>>>(bq, bk, bv, bqkv);

    embed_k<<<ROWS, 256, 0, stream>>>(x, tok, pos, hb, hq);

    for (int i = 0; i < NLAY; i++) {
        for (int j = 0; j < 2; j++) {
            int ij = i * 2 + j;
            // fused QKV projection (fp8 in, bf16 out [ROWS][2304])
            gemm128_f8<<<dim3(QKV / 128, ROWS / 128, 1), 256, 0, stream>>>(
                hq, WqkvT8 + (size_t)ij * QKV * DIM, DIM,
                bqkv + (size_t)ij * QKV, qkvb, nullptr, QKV, 0);
            // P = exp(masked(QK^T/20)) + colsum partials — triangular grid
            gemm256<1><<<dim3(36, 1, BH), 512, 0, stream>>>(
                qkvb, QKV, qkvb + DIM, QKV, SEQ, SEQ, DHD,
                wbuf, SEQ,
                NH, (long)SEQ * QKV, (long)DHD, (long)SEQ * QKV, (long)DHD,
                (long)NH * SEQ * SEQ, (long)SEQ * SEQ,
                x, cpart);
            // vT = transpose(v) scaled by 1/colsum (folds normalization into B)
            v_transpose<<<dim3(SEQ / 32, DHD / 32, BH), t32, 0, stream>>>(
                qkvb + 2 * DIM, QKV, cpart, vTb);
            // o = P @ vT  (bf16 out, causal K-truncation, balanced pairing)
            gemm128<3><<<dim3(2, SEQ / 128, BH), 256, 0, stream>>>(
                wbuf, SEQ, vTb, SEQ, DHD, SEQ,
                nullptr, ob, DIM, 0,
                NH, (long)NH * SEQ * SEQ, (long)SEQ * SEQ,
                (long)NH * DHD * SEQ, (long)DHD * SEQ,
                (long)SEQ * DIM, (long)DHD);
            resid_ln<<<ROWS, 256, 0, stream>>>(
                hb, ob, ln_g + (size_t)ij * DIM, ln_b + (size_t)ij * DIM, hb, hq);
        }
        // FF — fp8
        gemm128_f8<<<dim3(FFD / 128, ROWS / 128, 1), 256, 0, stream>>>(
            hq, W1T8 + (size_t)i * DIM * FFD, DIM,
            b1 + (size_t)i * FFD, nullptr, ff1q, FFD, 1);
        gemm128_f8<<<dim3(DIM / 128, ROWS / 128, 1), 256, 0, stream>>>(
            ff1q, W2T8 + (size_t)i * FFD * DIM, FFD,
            b2 + (size_t)i * DIM, ob, nullptr, DIM, 0);
        resid_ln<<<ROWS, 256, 0, stream>>>(
            hb, ob, f_g + (size_t)i * DIM, f_b + (size_t)i * DIM, hb, hq);
    }

    // classifier in fp8: streaming lse partials + label pick
    gemm256_f8<<<dim3(NT2, ROWS / 256, 1), 512, 0, stream>>>(
        hq, WcT8, DIM, bcls, label, partials, picked);
    lse_merge<<<ROWS, 256, 0, stream>>>(partials, lsev);
    loss_k<<<1, 256, 0, stream>>>(lsev, picked, (float*)d_out);
}